// Round 15
// baseline (252.836 us; speedup 1.0000x reference)
//
#include <hip/hip_runtime.h>
#include <hip/hip_bf16.h>

// ---------------------------------------------------------------------------
// Equivariant conv block. MFMA 32x32x16 implicit GEMM.
// R23 post-mortem: wrong pi RAISED conflicts 7.0->13.1M, conv +12us -> 1:1
// conflict<->time calibration confirmed. R24: derived-optimal swizzle.
// A-read quads have u-mod-16 in X0{0,5,8,13}/X2{2,7,10,15}/X4{1,4,9,12}/
// X6{3,6,11,14}; row stride 77 units (S=5). sigma maps X0,X4->even residues,
// X2,X6->odd, 4 distinct each; sigma4 (partial block, 12 units) agrees mod 8.
// => every 8-lane octet hits 8 DISTINCT bank groups; flat at all
// granularities (optimal under any monotone conflict model). Both-sides
// (rule #21): staging source uses sigma^-1, read uses sigma. Tables in
// __device__ const (setup-only, no scratch). Conv otherwise R20-verbatim;
// tail = R20 separate combine+finalize (252.2-verified).
// ---------------------------------------------------------------------------

using f4  = __attribute__((ext_vector_type(4)))  float;
using f16v= __attribute__((ext_vector_type(16))) float;
using s8  = __attribute__((ext_vector_type(8)))  short;  // 8 bf16

#define C_TOT 160
#define PZ_   37
#define NTAP  343
#define NROW  (4 * PZ_ * PZ_)   // 5476 (b,z,y) rows per chunk
#define KSN   8
#define SLICE_E 1048576         // bf16 elems per partial slice (4*64*4096)

#define AROW    1232
#define AE_ROWS 19
#define AO_ROWS 18
#define AO_OFF  23552
#define B_OFF   46080
#define BSZ     14336
#define LDS_SZ  (B_OFF + 2 * BSZ)   // 74752

// sigma / sigma^-1 on 16B-unit index within a row (76 units = 4x16 + 12).
__device__ const unsigned char SIG[16]  = {0,14,1,15,8,2,9,3,4,10,5,11,12,6,13,7};
__device__ const unsigned char ISIG[16] = {0,2,5,7,8,10,13,15,4,6,9,11,12,14,1,3};
__device__ const unsigned char SIG4[12]  = {0,6,1,7,8,2,9,3,4,10,5,11};
__device__ const unsigned char ISIG4[12] = {0,2,5,7,8,10,1,3,4,6,9,11};

__device__ __forceinline__ int pi_fwd(int u) {            // read-side
    return (u < 64) ? (u & ~15) | SIG[u & 15] : 64 + SIG4[u - 64];
}
__device__ __forceinline__ int pi_inv(int u) {            // stage-side
    return (u < 64) ? (u & ~15) | ISIG[u & 15] : 64 + ISIG4[u - 64];
}

__device__ __forceinline__ void gl_lds16(const void* g, void* l) {
    __builtin_amdgcn_global_load_lds(
        (const __attribute__((address_space(1))) unsigned int*)g,
        (__attribute__((address_space(3))) unsigned int*)l, 16, 0, 0);
}

__device__ __forceinline__ void pair_ij(int p, int& i, int& j) {
    if (p < 3)      { i = p; j = p; }
    else if (p == 3){ i = 0; j = 1; }
    else if (p == 4){ i = 0; j = 2; }
    else            { i = 1; j = 2; }
}

struct bf2 { __hip_bfloat16 x, y; };
struct bh4 { __hip_bfloat16 x, y, z, w; };

// ---------------------------------------------------------------------------
// build_w (R20): grid 343 = 1 block/tap, 192 threads.
// ---------------------------------------------------------------------------
__global__ void build_w_kernel(
    const float* __restrict__ b_ss, const float* __restrict__ w_ss,
    const float* __restrict__ b_sv, const float* __restrict__ w_sv,
    const float* __restrict__ b_st, const float* __restrict__ w_st,
    const float* __restrict__ b_vs, const float* __restrict__ w_vs,
    const float* __restrict__ b_vv, const float* __restrict__ w_vv,
    const float* __restrict__ b_vt, const float* __restrict__ w_vt,
    __hip_bfloat16* __restrict__ wl)
{
    __shared__ float S[13056];
    const int tid = threadIdx.x;          // 0..191
    const int tap = blockIdx.x;           // 0..342
    float* L = S;                         // 750
    float* W = S + 768;                   // 12288
    for (int r = tid; r < 750; r += 192) {
        float v;
        if (r < 3)        v = b_ss[r * NTAP + tap];
        else if (r < 12)  v = b_sv[(r - 3) * NTAP + tap];
        else if (r < 93)  v = b_st[(r - 12) * NTAP + tap];
        else if (r < 102) v = b_vs[(r - 93) * NTAP + tap];
        else if (r < 183) v = b_vv[(r - 102) * NTAP + tap];
        else              v = b_vt[(r - 183) * NTAP + tap];
        L[r] = v;
    }
    for (int r = tid; r < 12288; r += 192) {
        float v;
        if (r < 768)       v = w_ss[r];
        else if (r < 1536) v = w_sv[r - 768];
        else if (r < 3840) v = w_st[r - 1536];
        else if (r < 4608) v = w_vs[r - 3840];
        else if (r < 6912) v = w_vv[r - 4608];
        else               v = w_vt[r - 6912];
        W[r] = v;
    }
    __syncthreads();

    if (tid < 160) {
        const int c = tid;
        const int chunk = c >> 4, cw = c & 15;
        __hip_bfloat16* dst = wl + ((size_t)chunk * NTAP + tap) * 1024 + cw;

        if (c < 16) {
            const float l0 = L[0], l1 = L[1], l2 = L[2];
#pragma unroll
            for (int n = 0; n < 16; ++n) {
                const float* wr = &W[(n * 16 + c) * 3];
                dst[n * 16] = __float2bfloat16(wr[0]*l0 + wr[1]*l1 + wr[2]*l2);
            }
            float bv[3][3];
#pragma unroll
            for (int dn = 0; dn < 3; ++dn)
#pragma unroll
                for (int t = 0; t < 3; ++t) bv[dn][t] = L[93 + t*3 + dn];
#pragma unroll
            for (int u = 0; u < 16; ++u) {
                const float* wr = &W[3840 + (u * 16 + c) * 3];
                const float w0 = wr[0], w1 = wr[1], w2 = wr[2];
#pragma unroll
                for (int dn = 0; dn < 3; ++dn)
                    dst[(16 + u*3 + dn) * 16] = __float2bfloat16(
                        w0*bv[dn][0] + w1*bv[dn][1] + w2*bv[dn][2]);
            }
        } else if (c < 64) {
            const int mm = (c - 16) / 3, di = (c - 16) % 3;
            float bs0[3];
#pragma unroll
            for (int t = 0; t < 3; ++t) bs0[t] = L[3 + t*3 + di];
#pragma unroll
            for (int n = 0; n < 16; ++n) {
                const float* wr = &W[768 + (n * 16 + mm) * 3];
                dst[n * 16] = __float2bfloat16(
                    wr[0]*bs0[0] + wr[1]*bs0[1] + wr[2]*bs0[2]);
            }
            float bv[3][9];
#pragma unroll
            for (int dn = 0; dn < 3; ++dn)
#pragma unroll
                for (int t = 0; t < 9; ++t)
                    bv[dn][t] = L[102 + (t*3 + dn)*3 + di];
#pragma unroll
            for (int u = 0; u < 16; ++u) {
                const float* wr = &W[4608 + (u * 16 + mm) * 9];
                float a0 = 0.f, a1 = 0.f, a2 = 0.f;
#pragma unroll
                for (int t = 0; t < 9; ++t) {
                    const float wv = wr[t];
                    a0 += wv * bv[0][t]; a1 += wv * bv[1][t]; a2 += wv * bv[2][t];
                }
                dst[(16 + u*3 + 0) * 16] = __float2bfloat16(a0);
                dst[(16 + u*3 + 1) * 16] = __float2bfloat16(a1);
                dst[(16 + u*3 + 2) * 16] = __float2bfloat16(a2);
            }
        } else {
            const int q = c - 64, mm = q / 6, p = q % 6;
            int i, jj; pair_ij(p, i, jj);
            const int d1 = i*3 + jj, d2 = jj*3 + i;
            const bool dbl = (i != jj);
            float bs0[9];
#pragma unroll
            for (int t = 0; t < 9; ++t) {
                float b = L[12 + t*9 + d1];
                if (dbl) b += L[12 + t*9 + d2];
                bs0[t] = b;
            }
#pragma unroll
            for (int n = 0; n < 16; ++n) {
                const float* wr = &W[1536 + (n * 16 + mm) * 9];
                float acc = 0.f;
#pragma unroll
                for (int t = 0; t < 9; ++t) acc += wr[t] * bs0[t];
                dst[n * 16] = __float2bfloat16(acc);
            }
            float bv0[21], bv1[21], bv2[21];
#pragma unroll
            for (int t = 0; t < 21; ++t) {
                float x0 = L[183 + (t*3 + 0)*9 + d1];
                float x1 = L[183 + (t*3 + 1)*9 + d1];
                float x2 = L[183 + (t*3 + 2)*9 + d1];
                if (dbl) {
                    x0 += L[183 + (t*3 + 0)*9 + d2];
                    x1 += L[183 + (t*3 + 1)*9 + d2];
                    x2 += L[183 + (t*3 + 2)*9 + d2];
                }
                bv0[t] = x0; bv1[t] = x1; bv2[t] = x2;
            }
#pragma unroll
            for (int u = 0; u < 16; ++u) {
                const float* wr = &W[6912 + (u * 16 + mm) * 21];
                float a0 = 0.f, a1 = 0.f, a2 = 0.f;
#pragma unroll
                for (int t = 0; t < 21; ++t) {
                    const float wv = wr[t];
                    a0 += wv * bv0[t]; a1 += wv * bv1[t]; a2 += wv * bv2[t];
                }
                dst[(16 + u*3 + 0) * 16] = __float2bfloat16(a0);
                dst[(16 + u*3 + 1) * 16] = __float2bfloat16(a1);
                dst[(16 + u*3 + 2) * 16] = __float2bfloat16(a2);
            }
        }
    }
}

// ---------------------------------------------------------------------------
// build_xt: bid = (b*37 + z)*37 + y. xt[chunk][brow][s][16ch].
// ---------------------------------------------------------------------------
__global__ void build_xt_kernel(
    const float* __restrict__ sv, __hip_bfloat16* __restrict__ xt)
{
    __shared__ float row[2112];                  // 32*66
    const int tid = threadIdx.x;
    const int bid = blockIdx.x;                  // (b*37 + z)*37 + y
    const int y = bid % 37, z = (bid / 37) % 37, b = bid / 1369;
    const bool interior = (z >= 3 && z < 35 && y >= 3 && y < 35);
    if (interior) {
        const float* src = sv + (size_t)b * 2097152 + (z-3) * 1024 + (y-3) * 32;
        for (int f = tid; f < 2048; f += 256) {
            int ch = f >> 5, x = f & 31;
            row[x * 66 + ch] = src[(size_t)ch * 32768 + x];
        }
    }
    __syncthreads();
    for (int e2 = tid; e2 < 3040; e2 += 256) {
        const int chunk = e2 / 304;              // 0..9
        const int r     = e2 - chunk * 304;      // 0..303
        const int s     = r >> 3;                // 0..37
        const int cw    = (r & 7) * 2;
        const int c     = chunk * 16 + cw;
        float v0 = 0.f, v1 = 0.f;
        if (interior && s >= 3 && s < 35) {
            const int x = s - 3;
            if (c < 64) {
                v0 = row[x * 66 + c];
                v1 = row[x * 66 + c + 1];
            } else {
                int q = c - 64, u = q / 6, p = q % 6, i, j;
                pair_ij(p, i, j);
                v0 = row[x * 66 + 16 + u * 3 + i] * row[x * 66 + 16 + u * 3 + j];
                pair_ij(p + 1, i, j);
                v1 = row[x * 66 + 16 + u * 3 + i] * row[x * 66 + 16 + u * 3 + j];
            }
        }
        bf2 w{__float2bfloat16(v0), __float2bfloat16(v1)};
        *(bf2*)(xt + ((size_t)chunk * NROW + bid) * 608 + r * 2) = w;
    }
}

// ---------------------------------------------------------------------------
// Conv. Grid 512 (2 blocks/CU). R24 sigma-swizzle on A path:
// LDS unit L holds global unit pi_inv(L); reader addresses pi_fwd(2s+h).
// ---------------------------------------------------------------------------
__global__ __launch_bounds__(256, 2) void conv_mfma_kernel(
    const __hip_bfloat16* __restrict__ xt,
    const __hip_bfloat16* __restrict__ wl,
    __hip_bfloat16* __restrict__ y4b)
{
    __shared__ __align__(16) char lds[LDS_SZ];

    const int phys = blockIdx.x;
    const int bid  = (phys & 7) * (64 * KSN / 8) + (phys >> 3);

    const int low3 = bid & 7;
    const int rest = bid >> 3;
    const int ks   = rest % KSN;
    const int mb   = (rest / KSN) * 8 + low3;   // 0..63
    const int b    = mb >> 4;                   // 0..3
    const int oz   = mb & 15;                   // z-out 0..15

    const int tid  = threadIdx.x;
    const int w    = tid >> 6;
    const int lane = tid & 63;
    const int m    = lane & 31;
    const int h    = lane >> 5;

    // ---- A staging: LDS unit L <- global unit pi_inv(L) ----
    int invAE[6]; int nAE = 0;
#pragma unroll
    for (int k = 0; k < 6; ++k) {
        const int i = w + 4 * k;
        if (i < 23) {
            const int o = i * 1024 + lane * 16;
            int r = o / AROW;
            int rem = o - r * AROW;
            if (r > AE_ROWS - 1) { r = AE_ROWS - 1; rem = 0; }
            if (rem >= 1216) rem = 0;
            const int gu = pi_inv(rem >> 4);
            invAE[k] = (2 * r) * 608 + gu * 8;
            nAE = k + 1;
        }
    }
    int invAO[6]; int nAO = 0;
#pragma unroll
    for (int k = 0; k < 6; ++k) {
        const int i = w + 4 * k;
        if (i < 22) {
            const int o = i * 1024 + lane * 16;
            int r = o / AROW;
            int rem = o - r * AROW;
            if (r > AO_ROWS - 1) { r = AO_ROWS - 1; rem = 0; }
            if (rem >= 1216) rem = 0;
            const int gu = pi_inv(rem >> 4);
            invAO[k] = (2 * r + 1) * 608 + gu * 8;
            nAO = k + 1;
        }
    }
    int invB[4]; int nB = 0;
#pragma unroll
    for (int k = 0; k < 4; ++k) {
        const int i = w + 4 * k;
        if (i < 14) {
            const int kx = i >> 1, nt = i & 1;
            invB[k] = kx * 1024 + (nt * 32 + m) * 16 + h * 8;
            nB = k + 1;
        }
    }

    f16v acc[2][2];
    for (int t = 0; t < 2; ++t)
        for (int n = 0; n < 2; ++n)
            for (int k = 0; k < 16; ++k) acc[t][n][k] = 0.f;

    const int rA0   = ((m >> 4) << 2) + ((m >> 2) & 3);
    const int sbase = (w << 3) + ((m & 3) << 1);

    // ---- A-read byte offsets within row (swizzled), per kx ----
    int luA[7];
#pragma unroll
    for (int kx = 0; kx < 7; ++kx) {
        const int g = 2 * (sbase + kx) + h;     // global 16B unit 0..75
        luA[kx] = pi_fwd(g) * 16;
    }

    auto stageAE = [&](int g) {
        const int chunk = g / 7, kz = g - chunk * 7;
        const size_t u = ((size_t)chunk * NROW
                        + (size_t)(b * PZ_ + 2 * oz + kz) * PZ_) * 608;
#pragma unroll
        for (int k = 0; k < 6; ++k)
            if (k < nAE) gl_lds16(xt + u + invAE[k], lds + (w + 4 * k) * 1024);
    };
    auto stageAO = [&](int g) {
        const int chunk = g / 7, kz = g - chunk * 7;
        const size_t u = ((size_t)chunk * NROW
                        + (size_t)(b * PZ_ + 2 * oz + kz) * PZ_) * 608;
#pragma unroll
        for (int k = 0; k < 6; ++k)
            if (k < nAO) gl_lds16(xt + u + invAO[k], lds + AO_OFF + (w + 4 * k) * 1024);
    };
    auto stageB = [&](int g, int kyv, int bsel) {
        const int chunk = g / 7, kz = g - chunk * 7;
        const size_t u = ((size_t)chunk * NTAP + (size_t)(kz * 7 + kyv) * 7) * 1024;
        char* dst = lds + B_OFF + bsel * BSZ;
#pragma unroll
        for (int k = 0; k < 4; ++k)
            if (k < nB) gl_lds16(wl + u + invB[k], dst + (w + 4 * k) * 1024);
    };

    auto compute = [&](int ky, int bsel) {
        const int abase = (ky & 1) ? AO_OFF : 0;
        const char* abp = lds + abase + (rA0 + (ky >> 1)) * AROW;
        const char* bbp = lds + B_OFF + bsel * BSZ;
#pragma unroll
        for (int kx = 0; kx < 7; ++kx) {
            const char* ap = abp + luA[kx];
            const s8 a0 = *(const s8*)(ap);
            const s8 a1 = *(const s8*)(ap + 8 * AROW);
            const char* bp = bbp + kx * 2048 + h * 512 + m * 16;
            const s8 b0 = *(const s8*)(bp);
            const s8 b1 = *(const s8*)(bp + 1024);
            acc[0][0] = __builtin_amdgcn_mfma_f32_32x32x16_bf16(a0, b0, acc[0][0], 0, 0, 0);
            acc[0][1] = __builtin_amdgcn_mfma_f32_32x32x16_bf16(a0, b1, acc[0][1], 0, 0, 0);
            acc[1][0] = __builtin_amdgcn_mfma_f32_32x32x16_bf16(a1, b0, acc[1][0], 0, 0, 0);
            acc[1][1] = __builtin_amdgcn_mfma_f32_32x32x16_bf16(a1, b1, acc[1][1], 0, 0, 0);
        }
    };

    const int G = (70 - ks + KSN - 1) / KSN;
    const int T = G * 7;
    stageAO(ks);
    stageB(ks, 1, 0);
    __syncthreads();
    int bB = 0;
    for (int t = 0; t < T; ++t) {
        const int gi = t / 7, p = t - gi * 7;
        const int g  = ks + gi * KSN;
        const int ky = (p < 3) ? (2 * p + 1) : (2 * (p - 3));
        const int tn = t + 1;
        if (tn < T) {
            const int gin = tn / 7, pn = tn - gin * 7;
            const int kyn = (pn < 3) ? (2 * pn + 1) : (2 * (pn - 3));
            stageB(ks + gin * KSN, kyn, bB ^ 1);
        }
        if (p == 0) stageAE(g);
        else if (p == 3 && g + KSN < 70) stageAO(g + KSN);
        compute(ky, bB);
        __syncthreads();
        bB ^= 1;
    }

    // epilogue: two-pass LDS transpose, coalesced bf16 partial stores
    const int nl = lane & 31;
    f4* yb = (f4*)lds;
    __hip_bfloat16* dst0 = y4b + (size_t)ks * SLICE_E + (size_t)(b * 64) * 4096;
#pragma unroll
    for (int t = 0; t < 2; ++t) {
        __syncthreads();
#pragma unroll
        for (int nt = 0; nt < 2; ++nt) {
            const int n = nt * 32 + nl;
#pragma unroll
            for (int q = 0; q < 4; ++q) {
                const int rr = 2 * q + h;
                f4 v = { acc[t][nt][4*q], acc[t][nt][4*q+1],
                         acc[t][nt][4*q+2], acc[t][nt][4*q+3] };
                yb[n * 33 + rr * 4 + w] = v;
            }
        }
        __syncthreads();
        for (int j = tid; j < 2048; j += 256) {
            const int n  = j >> 5, sp = j & 31;
            f4 v = yb[n * 33 + sp];
            const int rr = sp >> 2, wq = sp & 3;
            const int yo = t * 8 + (rr >> 2) * 4 + (rr & 3);
            bh4 p{__float2bfloat16(v.x), __float2bfloat16(v.y),
                  __float2bfloat16(v.z), __float2bfloat16(v.w)};
            *(bh4*)(dst0 + (size_t)n * 4096 + oz * 256 + yo * 16 + wq * 4) = p;
        }
    }
}

// ---------------------------------------------------------------------------
// Combine KSN bf16 partials -> f32 yc + per-(n,b) sum of squares. 256 blocks.
// ---------------------------------------------------------------------------
__global__ void combine_reduce_kernel(const __hip_bfloat16* __restrict__ y4b,
                                      float* __restrict__ yc,
                                      float* __restrict__ sums2)
{
    const int n = blockIdx.x & 63, q = blockIdx.x >> 6;
    const size_t base = ((size_t)q * 64 + n) * 4096;
    float s = 0.f;
    for (int i = threadIdx.x; i < 1024; i += 256) {
        const size_t off = base + (size_t)i * 4;
        f4 v = {0.f, 0.f, 0.f, 0.f};
#pragma unroll
        for (int k = 0; k < KSN; ++k) {
            bh4 r = *(const bh4*)(y4b + off + (size_t)k * SLICE_E);
            v.x += (float)r.x; v.y += (float)r.y;
            v.z += (float)r.z; v.w += (float)r.w;
        }
        *(f4*)(yc + off) = v;
        s += v.x * v.x + v.y * v.y + v.z * v.z + v.w * v.w;
    }
    __shared__ float red[256];
    red[threadIdx.x] = s;
    __syncthreads();
    for (int st = 128; st > 0; st >>= 1) {
        if (threadIdx.x < st) red[threadIdx.x] += red[threadIdx.x + st];
        __syncthreads();
    }
    if (threadIdx.x == 0) sums2[n * 4 + q] = red[0];
}

// ---------------------------------------------------------------------------
__global__ void finalize_kernel(const float* __restrict__ yc,
                                const float* __restrict__ sums2,
                                const float* __restrict__ g_s,
                                const float* __restrict__ g_v,
                                const float* __restrict__ bias_s,
                                float* __restrict__ out)
{
    const int idx = blockIdx.x * 256 + threadIdx.x;   // exact grid, 1M
    const int n = (idx >> 12) & 63;
    float v = yc[idx];
    if (n < 16) {
        float sum = sums2[n*4] + sums2[n*4+1] + sums2[n*4+2] + sums2[n*4+3];
        float var = sum * (1.0f / 16384.0f);
        float sc  = g_s[n] / sqrtf(var + 1e-5f);
        v = fmaxf(v * sc + bias_s[n], 0.f);
    } else {
        int u = (n - 16) / 3;
        float sum = 0.f;
        for (int k = 0; k < 12; ++k) sum += sums2[(16 + u * 3) * 4 + k];
        float var = sum * (1.0f / 49152.0f);
        v = v * (g_v[u] / sqrtf(var + 1e-5f));
    }
    out[idx] = v;
}

// ---------------------------------------------------------------------------
extern "C" void kernel_launch(void* const* d_in, const int* in_sizes, int n_in,
                              void* d_out, int out_size, void* d_ws, size_t ws_size,
                              hipStream_t stream)
{
    const float* sv    = (const float*)d_in[0];
    const float* b_ss  = (const float*)d_in[1];
    const float* w_ss  = (const float*)d_in[2];
    const float* b_sv  = (const float*)d_in[3];
    const float* w_sv  = (const float*)d_in[4];
    const float* b_st  = (const float*)d_in[5];
    const float* w_st  = (const float*)d_in[6];
    const float* b_vs  = (const float*)d_in[7];
    const float* w_vs  = (const float*)d_in[8];
    const float* b_vv  = (const float*)d_in[9];
    const float* w_vv  = (const float*)d_in[10];
    const float* b_vt  = (const float*)d_in[11];
    const float* w_vt  = (const float*)d_in[12];
    const float* bn_gs = (const float*)d_in[13];
    const float* bn_gv = (const float*)d_in[14];
    const float* bias_s= (const float*)d_in[15];
    float* out = (float*)d_out;

    char* ws = (char*)d_ws;
    constexpr size_t XT_BYTES = (size_t)10 * NROW * 1216;      // 66,588,160
    constexpr size_t WL_BYTES = (size_t)10 * NTAP * 2048;      //  7,024,640
    constexpr size_t Y4_BYTES = (size_t)KSN * SLICE_E * 2;     // 16,777,216
    constexpr size_t YC_BYTES = (size_t)4 * 64 * 4096 * 4;     //  4,194,304

    __hip_bfloat16* xt  = (__hip_bfloat16*)ws;
    __hip_bfloat16* wl  = (__hip_bfloat16*)(ws + XT_BYTES);
    __hip_bfloat16* y4b = (__hip_bfloat16*)(ws + XT_BYTES + WL_BYTES);
    float* yc    = (float*)(ws + XT_BYTES + WL_BYTES + Y4_BYTES);
    float* sums2 = (float*)(ws + XT_BYTES + WL_BYTES + Y4_BYTES + YC_BYTES);

    build_xt_kernel<<<5476, 256, 0, stream>>>(sv, xt);
    build_w_kernel<<<343, 192, 0, stream>>>(
        b_ss, w_ss, b_sv, w_sv, b_st, w_st, b_vs, w_vs, b_vv, w_vv,
        b_vt, w_vt, wl);
    conv_mfma_kernel<<<64 * KSN, 256, 0, stream>>>(xt, wl, y4b);
    combine_reduce_kernel<<<256, 256, 0, stream>>>(y4b, yc, sums2);
    finalize_kernel<<<4096, 256, 0, stream>>>(yc, sums2, bn_gs, bn_gv, bias_s, out);
}

// Round 16
// 248.371 us; speedup vs baseline: 1.0180x; 1.0180x over previous
//
#include <hip/hip_runtime.h>
#include <hip/hip_bf16.h>

// ---------------------------------------------------------------------------
// Equivariant conv block. MFMA 32x32x16 implicit GEMM.
// R24 post-mortem: swizzle killed conflicts 7.0M->627K (derivation correct)
// with ZERO time gain -> baseline conflicts were hidden 2-way, not critical
// path; lever closed; conv reverted to R20-verbatim (best-verified ~106.5).
// Total-level noise measured +-5-8us (R23 247.0 w/ conv 118 vs R24 252.8 w/
// conv 108.8) -> judge by per-dispatch durations only.
// R25 lever: build_w occupancy. 343 blocks x 192thr = 1 wave/SIMD (zero
// latency hiding on serial chains). Split per-tap work by (n,u)-half:
// grid 686 (tap=bid>>1, H=bid&1), per-thread chains halve, ~3 blocks/CU
// where co-resident. Staging duplicated (L2-resident, ~1us aggregate).
// ---------------------------------------------------------------------------

using f4  = __attribute__((ext_vector_type(4)))  float;
using f16v= __attribute__((ext_vector_type(16))) float;
using s8  = __attribute__((ext_vector_type(8)))  short;  // 8 bf16

#define C_TOT 160
#define PZ_   37
#define NTAP  343
#define NROW  (4 * PZ_ * PZ_)   // 5476 (b,z,y) rows per chunk
#define KSN   8
#define SLICE_E 1048576         // bf16 elems per partial slice (4*64*4096)

#define AROW    1232
#define AE_ROWS 19
#define AO_ROWS 18
#define AO_OFF  23552
#define B_OFF   46080
#define BSZ     14336
#define LDS_SZ  (B_OFF + 2 * BSZ)   // 74752

__device__ __forceinline__ void gl_lds16(const void* g, void* l) {
    __builtin_amdgcn_global_load_lds(
        (const __attribute__((address_space(1))) unsigned int*)g,
        (__attribute__((address_space(3))) unsigned int*)l, 16, 0, 0);
}

__device__ __forceinline__ void pair_ij(int p, int& i, int& j) {
    if (p < 3)      { i = p; j = p; }
    else if (p == 3){ i = 0; j = 1; }
    else if (p == 4){ i = 0; j = 2; }
    else            { i = 1; j = 2; }
}

struct bf2 { __hip_bfloat16 x, y; };
struct bh4 { __hip_bfloat16 x, y, z, w; };

// ---------------------------------------------------------------------------
// build_w (R25): grid 686 = 2 blocks/tap (H = n/u half), 192 threads.
// Threads 0..159 own channel-column c; compute n in [8H,8H+8) and
// u in [8H,8H+8) with register-hoisted basis combos.
// ---------------------------------------------------------------------------
__global__ void build_w_kernel(
    const float* __restrict__ b_ss, const float* __restrict__ w_ss,
    const float* __restrict__ b_sv, const float* __restrict__ w_sv,
    const float* __restrict__ b_st, const float* __restrict__ w_st,
    const float* __restrict__ b_vs, const float* __restrict__ w_vs,
    const float* __restrict__ b_vv, const float* __restrict__ w_vv,
    const float* __restrict__ b_vt, const float* __restrict__ w_vt,
    __hip_bfloat16* __restrict__ wl)
{
    __shared__ float S[13056];
    const int tid = threadIdx.x;          // 0..191
    const int tap = blockIdx.x >> 1;      // 0..342
    const int H   = blockIdx.x & 1;       // half select
    const int n0  = 8 * H;
    float* L = S;                         // 750
    float* W = S + 768;                   // 12288
    for (int r = tid; r < 750; r += 192) {
        float v;
        if (r < 3)        v = b_ss[r * NTAP + tap];
        else if (r < 12)  v = b_sv[(r - 3) * NTAP + tap];
        else if (r < 93)  v = b_st[(r - 12) * NTAP + tap];
        else if (r < 102) v = b_vs[(r - 93) * NTAP + tap];
        else if (r < 183) v = b_vv[(r - 102) * NTAP + tap];
        else              v = b_vt[(r - 183) * NTAP + tap];
        L[r] = v;
    }
    for (int r = tid; r < 12288; r += 192) {
        float v;
        if (r < 768)       v = w_ss[r];
        else if (r < 1536) v = w_sv[r - 768];
        else if (r < 3840) v = w_st[r - 1536];
        else if (r < 4608) v = w_vs[r - 3840];
        else if (r < 6912) v = w_vv[r - 4608];
        else               v = w_vt[r - 6912];
        W[r] = v;
    }
    __syncthreads();

    if (tid < 160) {
        const int c = tid;
        const int chunk = c >> 4, cw = c & 15;
        __hip_bfloat16* dst = wl + ((size_t)chunk * NTAP + tap) * 1024 + cw;

        if (c < 16) {
            const float l0 = L[0], l1 = L[1], l2 = L[2];
#pragma unroll
            for (int nn = 0; nn < 8; ++nn) {
                const int n = n0 + nn;
                const float* wr = &W[(n * 16 + c) * 3];
                dst[n * 16] = __float2bfloat16(wr[0]*l0 + wr[1]*l1 + wr[2]*l2);
            }
            float bv[3][3];
#pragma unroll
            for (int dn = 0; dn < 3; ++dn)
#pragma unroll
                for (int t = 0; t < 3; ++t) bv[dn][t] = L[93 + t*3 + dn];
#pragma unroll
            for (int uu = 0; uu < 8; ++uu) {
                const int u = n0 + uu;
                const float* wr = &W[3840 + (u * 16 + c) * 3];
                const float w0 = wr[0], w1 = wr[1], w2 = wr[2];
#pragma unroll
                for (int dn = 0; dn < 3; ++dn)
                    dst[(16 + u*3 + dn) * 16] = __float2bfloat16(
                        w0*bv[dn][0] + w1*bv[dn][1] + w2*bv[dn][2]);
            }
        } else if (c < 64) {
            const int mm = (c - 16) / 3, di = (c - 16) % 3;
            float bs0[3];
#pragma unroll
            for (int t = 0; t < 3; ++t) bs0[t] = L[3 + t*3 + di];
#pragma unroll
            for (int nn = 0; nn < 8; ++nn) {
                const int n = n0 + nn;
                const float* wr = &W[768 + (n * 16 + mm) * 3];
                dst[n * 16] = __float2bfloat16(
                    wr[0]*bs0[0] + wr[1]*bs0[1] + wr[2]*bs0[2]);
            }
            float bv[3][9];
#pragma unroll
            for (int dn = 0; dn < 3; ++dn)
#pragma unroll
                for (int t = 0; t < 9; ++t)
                    bv[dn][t] = L[102 + (t*3 + dn)*3 + di];
#pragma unroll
            for (int uu = 0; uu < 8; ++uu) {
                const int u = n0 + uu;
                const float* wr = &W[4608 + (u * 16 + mm) * 9];
                float a0 = 0.f, a1 = 0.f, a2 = 0.f;
#pragma unroll
                for (int t = 0; t < 9; ++t) {
                    const float wv = wr[t];
                    a0 += wv * bv[0][t]; a1 += wv * bv[1][t]; a2 += wv * bv[2][t];
                }
                dst[(16 + u*3 + 0) * 16] = __float2bfloat16(a0);
                dst[(16 + u*3 + 1) * 16] = __float2bfloat16(a1);
                dst[(16 + u*3 + 2) * 16] = __float2bfloat16(a2);
            }
        } else {
            const int q = c - 64, mm = q / 6, p = q % 6;
            int i, jj; pair_ij(p, i, jj);
            const int d1 = i*3 + jj, d2 = jj*3 + i;
            const bool dbl = (i != jj);
            float bs0[9];
#pragma unroll
            for (int t = 0; t < 9; ++t) {
                float b = L[12 + t*9 + d1];
                if (dbl) b += L[12 + t*9 + d2];
                bs0[t] = b;
            }
#pragma unroll
            for (int nn = 0; nn < 8; ++nn) {
                const int n = n0 + nn;
                const float* wr = &W[1536 + (n * 16 + mm) * 9];
                float acc = 0.f;
#pragma unroll
                for (int t = 0; t < 9; ++t) acc += wr[t] * bs0[t];
                dst[n * 16] = __float2bfloat16(acc);
            }
            float bv0[21], bv1[21], bv2[21];
#pragma unroll
            for (int t = 0; t < 21; ++t) {
                float x0 = L[183 + (t*3 + 0)*9 + d1];
                float x1 = L[183 + (t*3 + 1)*9 + d1];
                float x2 = L[183 + (t*3 + 2)*9 + d1];
                if (dbl) {
                    x0 += L[183 + (t*3 + 0)*9 + d2];
                    x1 += L[183 + (t*3 + 1)*9 + d2];
                    x2 += L[183 + (t*3 + 2)*9 + d2];
                }
                bv0[t] = x0; bv1[t] = x1; bv2[t] = x2;
            }
#pragma unroll
            for (int uu = 0; uu < 8; ++uu) {
                const int u = n0 + uu;
                const float* wr = &W[6912 + (u * 16 + mm) * 21];
                float a0 = 0.f, a1 = 0.f, a2 = 0.f;
#pragma unroll
                for (int t = 0; t < 21; ++t) {
                    const float wv = wr[t];
                    a0 += wv * bv0[t]; a1 += wv * bv1[t]; a2 += wv * bv2[t];
                }
                dst[(16 + u*3 + 0) * 16] = __float2bfloat16(a0);
                dst[(16 + u*3 + 1) * 16] = __float2bfloat16(a1);
                dst[(16 + u*3 + 2) * 16] = __float2bfloat16(a2);
            }
        }
    }
}

// ---------------------------------------------------------------------------
// build_xt: bid = (b*37 + z)*37 + y. xt[chunk][brow][s][16ch].
// ---------------------------------------------------------------------------
__global__ void build_xt_kernel(
    const float* __restrict__ sv, __hip_bfloat16* __restrict__ xt)
{
    __shared__ float row[2112];                  // 32*66
    const int tid = threadIdx.x;
    const int bid = blockIdx.x;                  // (b*37 + z)*37 + y
    const int y = bid % 37, z = (bid / 37) % 37, b = bid / 1369;
    const bool interior = (z >= 3 && z < 35 && y >= 3 && y < 35);
    if (interior) {
        const float* src = sv + (size_t)b * 2097152 + (z-3) * 1024 + (y-3) * 32;
        for (int f = tid; f < 2048; f += 256) {
            int ch = f >> 5, x = f & 31;
            row[x * 66 + ch] = src[(size_t)ch * 32768 + x];
        }
    }
    __syncthreads();
    for (int e2 = tid; e2 < 3040; e2 += 256) {
        const int chunk = e2 / 304;              // 0..9
        const int r     = e2 - chunk * 304;      // 0..303
        const int s     = r >> 3;                // 0..37
        const int cw    = (r & 7) * 2;
        const int c     = chunk * 16 + cw;
        float v0 = 0.f, v1 = 0.f;
        if (interior && s >= 3 && s < 35) {
            const int x = s - 3;
            if (c < 64) {
                v0 = row[x * 66 + c];
                v1 = row[x * 66 + c + 1];
            } else {
                int q = c - 64, u = q / 6, p = q % 6, i, j;
                pair_ij(p, i, j);
                v0 = row[x * 66 + 16 + u * 3 + i] * row[x * 66 + 16 + u * 3 + j];
                pair_ij(p + 1, i, j);
                v1 = row[x * 66 + 16 + u * 3 + i] * row[x * 66 + 16 + u * 3 + j];
            }
        }
        bf2 w{__float2bfloat16(v0), __float2bfloat16(v1)};
        *(bf2*)(xt + ((size_t)chunk * NROW + bid) * 608 + r * 2) = w;
    }
}

// ---------------------------------------------------------------------------
// Conv (R20-verbatim, best-verified ~106.5us). Grid 512 (2 blocks/CU).
// ---------------------------------------------------------------------------
__global__ __launch_bounds__(256, 2) void conv_mfma_kernel(
    const __hip_bfloat16* __restrict__ xt,
    const __hip_bfloat16* __restrict__ wl,
    __hip_bfloat16* __restrict__ y4b)
{
    __shared__ __align__(16) char lds[LDS_SZ];

    const int phys = blockIdx.x;
    const int bid  = (phys & 7) * (64 * KSN / 8) + (phys >> 3);

    const int low3 = bid & 7;
    const int rest = bid >> 3;
    const int ks   = rest % KSN;
    const int mb   = (rest / KSN) * 8 + low3;   // 0..63
    const int b    = mb >> 4;                   // 0..3
    const int oz   = mb & 15;                   // z-out 0..15

    const int tid  = threadIdx.x;
    const int w    = tid >> 6;
    const int lane = tid & 63;
    const int m    = lane & 31;
    const int h    = lane >> 5;

    int invAE[6]; int nAE = 0;
#pragma unroll
    for (int k = 0; k < 6; ++k) {
        const int i = w + 4 * k;
        if (i < 23) {
            const int o = i * 1024 + lane * 16;
            int r = o / AROW;
            int rem = o - r * AROW;
            if (r > AE_ROWS - 1) { r = AE_ROWS - 1; rem = 0; }
            if (rem >= 1216) rem = 0;
            const int s  = rem >> 5;
            const int cg = ((rem >> 4) & 1) ^ ((s >> 1) & 1);
            invAE[k] = (2 * r) * 608 + s * 16 + cg * 8;
            nAE = k + 1;
        }
    }
    int invAO[6]; int nAO = 0;
#pragma unroll
    for (int k = 0; k < 6; ++k) {
        const int i = w + 4 * k;
        if (i < 22) {
            const int o = i * 1024 + lane * 16;
            int r = o / AROW;
            int rem = o - r * AROW;
            if (r > AO_ROWS - 1) { r = AO_ROWS - 1; rem = 0; }
            if (rem >= 1216) rem = 0;
            const int s  = rem >> 5;
            const int cg = ((rem >> 4) & 1) ^ ((s >> 1) & 1);
            invAO[k] = (2 * r + 1) * 608 + s * 16 + cg * 8;
            nAO = k + 1;
        }
    }
    int invB[4]; int nB = 0;
#pragma unroll
    for (int k = 0; k < 4; ++k) {
        const int i = w + 4 * k;
        if (i < 14) {
            const int kx = i >> 1, nt = i & 1;
            invB[k] = kx * 1024 + (nt * 32 + m) * 16 + h * 8;
            nB = k + 1;
        }
    }

    f16v acc[2][2];
    for (int t = 0; t < 2; ++t)
        for (int n = 0; n < 2; ++n)
            for (int k = 0; k < 16; ++k) acc[t][n][k] = 0.f;

    const int rA0   = ((m >> 4) << 2) + ((m >> 2) & 3);
    const int sbase = (w << 3) + ((m & 3) << 1);

    auto stageAE = [&](int g) {
        const int chunk = g / 7, kz = g - chunk * 7;
        const size_t u = ((size_t)chunk * NROW
                        + (size_t)(b * PZ_ + 2 * oz + kz) * PZ_) * 608;
#pragma unroll
        for (int k = 0; k < 6; ++k)
            if (k < nAE) gl_lds16(xt + u + invAE[k], lds + (w + 4 * k) * 1024);
    };
    auto stageAO = [&](int g) {
        const int chunk = g / 7, kz = g - chunk * 7;
        const size_t u = ((size_t)chunk * NROW
                        + (size_t)(b * PZ_ + 2 * oz + kz) * PZ_) * 608;
#pragma unroll
        for (int k = 0; k < 6; ++k)
            if (k < nAO) gl_lds16(xt + u + invAO[k], lds + AO_OFF + (w + 4 * k) * 1024);
    };
    auto stageB = [&](int g, int kyv, int bsel) {
        const int chunk = g / 7, kz = g - chunk * 7;
        const size_t u = ((size_t)chunk * NTAP + (size_t)(kz * 7 + kyv) * 7) * 1024;
        char* dst = lds + B_OFF + bsel * BSZ;
#pragma unroll
        for (int k = 0; k < 4; ++k)
            if (k < nB) gl_lds16(wl + u + invB[k], dst + (w + 4 * k) * 1024);
    };

    auto compute = [&](int ky, int bsel) {
        const int abase = (ky & 1) ? AO_OFF : 0;
        const char* abp = lds + abase + (rA0 + (ky >> 1)) * AROW;
        const char* bbp = lds + B_OFF + bsel * BSZ;
#pragma unroll
        for (int kx = 0; kx < 7; ++kx) {
            const int s   = sbase + kx;
            const int cgp = h ^ ((s >> 1) & 1);
            const char* ap = abp + s * 32 + cgp * 16;
            const s8 a0 = *(const s8*)(ap);
            const s8 a1 = *(const s8*)(ap + 8 * AROW);
            const char* bp = bbp + kx * 2048 + h * 512 + m * 16;
            const s8 b0 = *(const s8*)(bp);
            const s8 b1 = *(const s8*)(bp + 1024);
            acc[0][0] = __builtin_amdgcn_mfma_f32_32x32x16_bf16(a0, b0, acc[0][0], 0, 0, 0);
            acc[0][1] = __builtin_amdgcn_mfma_f32_32x32x16_bf16(a0, b1, acc[0][1], 0, 0, 0);
            acc[1][0] = __builtin_amdgcn_mfma_f32_32x32x16_bf16(a1, b0, acc[1][0], 0, 0, 0);
            acc[1][1] = __builtin_amdgcn_mfma_f32_32x32x16_bf16(a1, b1, acc[1][1], 0, 0, 0);
        }
    };

    const int G = (70 - ks + KSN - 1) / KSN;
    const int T = G * 7;
    stageAO(ks);
    stageB(ks, 1, 0);
    __syncthreads();
    int bB = 0;
    for (int t = 0; t < T; ++t) {
        const int gi = t / 7, p = t - gi * 7;
        const int g  = ks + gi * KSN;
        const int ky = (p < 3) ? (2 * p + 1) : (2 * (p - 3));
        const int tn = t + 1;
        if (tn < T) {
            const int gin = tn / 7, pn = tn - gin * 7;
            const int kyn = (pn < 3) ? (2 * pn + 1) : (2 * (pn - 3));
            stageB(ks + gin * KSN, kyn, bB ^ 1);
        }
        if (p == 0) stageAE(g);
        else if (p == 3 && g + KSN < 70) stageAO(g + KSN);
        compute(ky, bB);
        __syncthreads();
        bB ^= 1;
    }

    // epilogue: two-pass LDS transpose, coalesced bf16 partial stores
    const int nl = lane & 31;
    f4* yb = (f4*)lds;
    __hip_bfloat16* dst0 = y4b + (size_t)ks * SLICE_E + (size_t)(b * 64) * 4096;
#pragma unroll
    for (int t = 0; t < 2; ++t) {
        __syncthreads();
#pragma unroll
        for (int nt = 0; nt < 2; ++nt) {
            const int n = nt * 32 + nl;
#pragma unroll
            for (int q = 0; q < 4; ++q) {
                const int rr = 2 * q + h;
                f4 v = { acc[t][nt][4*q], acc[t][nt][4*q+1],
                         acc[t][nt][4*q+2], acc[t][nt][4*q+3] };
                yb[n * 33 + rr * 4 + w] = v;
            }
        }
        __syncthreads();
        for (int j = tid; j < 2048; j += 256) {
            const int n  = j >> 5, sp = j & 31;
            f4 v = yb[n * 33 + sp];
            const int rr = sp >> 2, wq = sp & 3;
            const int yo = t * 8 + (rr >> 2) * 4 + (rr & 3);
            bh4 p{__float2bfloat16(v.x), __float2bfloat16(v.y),
                  __float2bfloat16(v.z), __float2bfloat16(v.w)};
            *(bh4*)(dst0 + (size_t)n * 4096 + oz * 256 + yo * 16 + wq * 4) = p;
        }
    }
}

// ---------------------------------------------------------------------------
// Combine KSN bf16 partials -> f32 yc + per-(n,b) sum of squares. 256 blocks.
// ---------------------------------------------------------------------------
__global__ void combine_reduce_kernel(const __hip_bfloat16* __restrict__ y4b,
                                      float* __restrict__ yc,
                                      float* __restrict__ sums2)
{
    const int n = blockIdx.x & 63, q = blockIdx.x >> 6;
    const size_t base = ((size_t)q * 64 + n) * 4096;
    float s = 0.f;
    for (int i = threadIdx.x; i < 1024; i += 256) {
        const size_t off = base + (size_t)i * 4;
        f4 v = {0.f, 0.f, 0.f, 0.f};
#pragma unroll
        for (int k = 0; k < KSN; ++k) {
            bh4 r = *(const bh4*)(y4b + off + (size_t)k * SLICE_E);
            v.x += (float)r.x; v.y += (float)r.y;
            v.z += (float)r.z; v.w += (float)r.w;
        }
        *(f4*)(yc + off) = v;
        s += v.x * v.x + v.y * v.y + v.z * v.z + v.w * v.w;
    }
    __shared__ float red[256];
    red[threadIdx.x] = s;
    __syncthreads();
    for (int st = 128; st > 0; st >>= 1) {
        if (threadIdx.x < st) red[threadIdx.x] += red[threadIdx.x + st];
        __syncthreads();
    }
    if (threadIdx.x == 0) sums2[n * 4 + q] = red[0];
}

// ---------------------------------------------------------------------------
__global__ void finalize_kernel(const float* __restrict__ yc,
                                const float* __restrict__ sums2,
                                const float* __restrict__ g_s,
                                const float* __restrict__ g_v,
                                const float* __restrict__ bias_s,
                                float* __restrict__ out)
{
    const int idx = blockIdx.x * 256 + threadIdx.x;   // exact grid, 1M
    const int n = (idx >> 12) & 63;
    float v = yc[idx];
    if (n < 16) {
        float sum = sums2[n*4] + sums2[n*4+1] + sums2[n*4+2] + sums2[n*4+3];
        float var = sum * (1.0f / 16384.0f);
        float sc  = g_s[n] / sqrtf(var + 1e-5f);
        v = fmaxf(v * sc + bias_s[n], 0.f);
    } else {
        int u = (n - 16) / 3;
        float sum = 0.f;
        for (int k = 0; k < 12; ++k) sum += sums2[(16 + u * 3) * 4 + k];
        float var = sum * (1.0f / 49152.0f);
        v = v * (g_v[u] / sqrtf(var + 1e-5f));
    }
    out[idx] = v;
}

// ---------------------------------------------------------------------------
extern "C" void kernel_launch(void* const* d_in, const int* in_sizes, int n_in,
                              void* d_out, int out_size, void* d_ws, size_t ws_size,
                              hipStream_t stream)
{
    const float* sv    = (const float*)d_in[0];
    const float* b_ss  = (const float*)d_in[1];
    const float* w_ss  = (const float*)d_in[2];
    const float* b_sv  = (const float*)d_in[3];
    const float* w_sv  = (const float*)d_in[4];
    const float* b_st  = (const float*)d_in[5];
    const float* w_st  = (const float*)d_in[6];
    const float* b_vs  = (const float*)d_in[7];
    const float* w_vs  = (const float*)d_in[8];
    const float* b_vv  = (const float*)d_in[9];
    const float* w_vv  = (const float*)d_in[10];
    const float* b_vt  = (const float*)d_in[11];
    const float* w_vt  = (const float*)d_in[12];
    const float* bn_gs = (const float*)d_in[13];
    const float* bn_gv = (const float*)d_in[14];
    const float* bias_s= (const float*)d_in[15];
    float* out = (float*)d_out;

    char* ws = (char*)d_ws;
    constexpr size_t XT_BYTES = (size_t)10 * NROW * 1216;      // 66,588,160
    constexpr size_t WL_BYTES = (size_t)10 * NTAP * 2048;      //  7,024,640
    constexpr size_t Y4_BYTES = (size_t)KSN * SLICE_E * 2;     // 16,777,216
    constexpr size_t YC_BYTES = (size_t)4 * 64 * 4096 * 4;     //  4,194,304

    __hip_bfloat16* xt  = (__hip_bfloat16*)ws;
    __hip_bfloat16* wl  = (__hip_bfloat16*)(ws + XT_BYTES);
    __hip_bfloat16* y4b = (__hip_bfloat16*)(ws + XT_BYTES + WL_BYTES);
    float* yc    = (float*)(ws + XT_BYTES + WL_BYTES + Y4_BYTES);
    float* sums2 = (float*)(ws + XT_BYTES + WL_BYTES + Y4_BYTES + YC_BYTES);

    build_xt_kernel<<<5476, 256, 0, stream>>>(sv, xt);
    build_w_kernel<<<686, 192, 0, stream>>>(
        b_ss, w_ss, b_sv, w_sv, b_st, w_st, b_vs, w_vs, b_vv, w_vv,
        b_vt, w_vt, wl);
    conv_mfma_kernel<<<64 * KSN, 256, 0, stream>>>(xt, wl, y4b);
    combine_reduce_kernel<<<256, 256, 0, stream>>>(y4b, yc, sums2);
    finalize_kernel<<<4096, 256, 0, stream>>>(yc, sums2, bn_gs, bn_gv, bias_s, out);
}

// Round 18
// 247.256 us; speedup vs baseline: 1.0226x; 1.0045x over previous
//
#include <hip/hip_runtime.h>
#include <hip/hip_bf16.h>

// ---------------------------------------------------------------------------
// Equivariant conv block. MFMA 32x32x16 implicit GEMM.
// R25: build_w split (grid 686) kept — conv 104.8-105.1, total 248.4.
// Conv invariant 105-107 across staged-bytes/barriers/occupancy/conflicts;
// LDS-pipe floor ~69us, MFMA ~47us -> 1.4x floor, schedule-insensitive.
// R26 (last identified lever): T5 s_setprio(1) around the MFMA cluster.
// Mechanism: 2 blocks/CU with different ks drift out of phase -> wave
// role-split (stage vs MFMA) -> scheduler can favor MFMA-entering waves
// (catalog: +4-7% when role-diverse, null when lockstep). Zero risk.
// Pre-commit: conv >=104 -> plateau declared next round.
// R27 = R26 resubmitted unchanged (container acquisition failed; experiment
// never ran).
// ---------------------------------------------------------------------------

using f4  = __attribute__((ext_vector_type(4)))  float;
using f16v= __attribute__((ext_vector_type(16))) float;
using s8  = __attribute__((ext_vector_type(8)))  short;  // 8 bf16

#define C_TOT 160
#define PZ_   37
#define NTAP  343
#define NROW  (4 * PZ_ * PZ_)   // 5476 (b,z,y) rows per chunk
#define KSN   8
#define SLICE_E 1048576         // bf16 elems per partial slice (4*64*4096)

#define AROW    1232
#define AE_ROWS 19
#define AO_ROWS 18
#define AO_OFF  23552
#define B_OFF   46080
#define BSZ     14336
#define LDS_SZ  (B_OFF + 2 * BSZ)   // 74752

__device__ __forceinline__ void gl_lds16(const void* g, void* l) {
    __builtin_amdgcn_global_load_lds(
        (const __attribute__((address_space(1))) unsigned int*)g,
        (__attribute__((address_space(3))) unsigned int*)l, 16, 0, 0);
}

__device__ __forceinline__ void pair_ij(int p, int& i, int& j) {
    if (p < 3)      { i = p; j = p; }
    else if (p == 3){ i = 0; j = 1; }
    else if (p == 4){ i = 0; j = 2; }
    else            { i = 1; j = 2; }
}

struct bf2 { __hip_bfloat16 x, y; };
struct bh4 { __hip_bfloat16 x, y, z, w; };

// ---------------------------------------------------------------------------
// build_w (R25): grid 686 = 2 blocks/tap (H = n/u half), 192 threads.
// ---------------------------------------------------------------------------
__global__ void build_w_kernel(
    const float* __restrict__ b_ss, const float* __restrict__ w_ss,
    const float* __restrict__ b_sv, const float* __restrict__ w_sv,
    const float* __restrict__ b_st, const float* __restrict__ w_st,
    const float* __restrict__ b_vs, const float* __restrict__ w_vs,
    const float* __restrict__ b_vv, const float* __restrict__ w_vv,
    const float* __restrict__ b_vt, const float* __restrict__ w_vt,
    __hip_bfloat16* __restrict__ wl)
{
    __shared__ float S[13056];
    const int tid = threadIdx.x;          // 0..191
    const int tap = blockIdx.x >> 1;      // 0..342
    const int H   = blockIdx.x & 1;       // half select
    const int n0  = 8 * H;
    float* L = S;                         // 750
    float* W = S + 768;                   // 12288
    for (int r = tid; r < 750; r += 192) {
        float v;
        if (r < 3)        v = b_ss[r * NTAP + tap];
        else if (r < 12)  v = b_sv[(r - 3) * NTAP + tap];
        else if (r < 93)  v = b_st[(r - 12) * NTAP + tap];
        else if (r < 102) v = b_vs[(r - 93) * NTAP + tap];
        else if (r < 183) v = b_vv[(r - 102) * NTAP + tap];
        else              v = b_vt[(r - 183) * NTAP + tap];
        L[r] = v;
    }
    for (int r = tid; r < 12288; r += 192) {
        float v;
        if (r < 768)       v = w_ss[r];
        else if (r < 1536) v = w_sv[r - 768];
        else if (r < 3840) v = w_st[r - 1536];
        else if (r < 4608) v = w_vs[r - 3840];
        else if (r < 6912) v = w_vv[r - 4608];
        else               v = w_vt[r - 6912];
        W[r] = v;
    }
    __syncthreads();

    if (tid < 160) {
        const int c = tid;
        const int chunk = c >> 4, cw = c & 15;
        __hip_bfloat16* dst = wl + ((size_t)chunk * NTAP + tap) * 1024 + cw;

        if (c < 16) {
            const float l0 = L[0], l1 = L[1], l2 = L[2];
#pragma unroll
            for (int nn = 0; nn < 8; ++nn) {
                const int n = n0 + nn;
                const float* wr = &W[(n * 16 + c) * 3];
                dst[n * 16] = __float2bfloat16(wr[0]*l0 + wr[1]*l1 + wr[2]*l2);
            }
            float bv[3][3];
#pragma unroll
            for (int dn = 0; dn < 3; ++dn)
#pragma unroll
                for (int t = 0; t < 3; ++t) bv[dn][t] = L[93 + t*3 + dn];
#pragma unroll
            for (int uu = 0; uu < 8; ++uu) {
                const int u = n0 + uu;
                const float* wr = &W[3840 + (u * 16 + c) * 3];
                const float w0 = wr[0], w1 = wr[1], w2 = wr[2];
#pragma unroll
                for (int dn = 0; dn < 3; ++dn)
                    dst[(16 + u*3 + dn) * 16] = __float2bfloat16(
                        w0*bv[dn][0] + w1*bv[dn][1] + w2*bv[dn][2]);
            }
        } else if (c < 64) {
            const int mm = (c - 16) / 3, di = (c - 16) % 3;
            float bs0[3];
#pragma unroll
            for (int t = 0; t < 3; ++t) bs0[t] = L[3 + t*3 + di];
#pragma unroll
            for (int nn = 0; nn < 8; ++nn) {
                const int n = n0 + nn;
                const float* wr = &W[768 + (n * 16 + mm) * 3];
                dst[n * 16] = __float2bfloat16(
                    wr[0]*bs0[0] + wr[1]*bs0[1] + wr[2]*bs0[2]);
            }
            float bv[3][9];
#pragma unroll
            for (int dn = 0; dn < 3; ++dn)
#pragma unroll
                for (int t = 0; t < 9; ++t)
                    bv[dn][t] = L[102 + (t*3 + dn)*3 + di];
#pragma unroll
            for (int uu = 0; uu < 8; ++uu) {
                const int u = n0 + uu;
                const float* wr = &W[4608 + (u * 16 + mm) * 9];
                float a0 = 0.f, a1 = 0.f, a2 = 0.f;
#pragma unroll
                for (int t = 0; t < 9; ++t) {
                    const float wv = wr[t];
                    a0 += wv * bv[0][t]; a1 += wv * bv[1][t]; a2 += wv * bv[2][t];
                }
                dst[(16 + u*3 + 0) * 16] = __float2bfloat16(a0);
                dst[(16 + u*3 + 1) * 16] = __float2bfloat16(a1);
                dst[(16 + u*3 + 2) * 16] = __float2bfloat16(a2);
            }
        } else {
            const int q = c - 64, mm = q / 6, p = q % 6;
            int i, jj; pair_ij(p, i, jj);
            const int d1 = i*3 + jj, d2 = jj*3 + i;
            const bool dbl = (i != jj);
            float bs0[9];
#pragma unroll
            for (int t = 0; t < 9; ++t) {
                float b = L[12 + t*9 + d1];
                if (dbl) b += L[12 + t*9 + d2];
                bs0[t] = b;
            }
#pragma unroll
            for (int nn = 0; nn < 8; ++nn) {
                const int n = n0 + nn;
                const float* wr = &W[1536 + (n * 16 + mm) * 9];
                float acc = 0.f;
#pragma unroll
                for (int t = 0; t < 9; ++t) acc += wr[t] * bs0[t];
                dst[n * 16] = __float2bfloat16(acc);
            }
            float bv0[21], bv1[21], bv2[21];
#pragma unroll
            for (int t = 0; t < 21; ++t) {
                float x0 = L[183 + (t*3 + 0)*9 + d1];
                float x1 = L[183 + (t*3 + 1)*9 + d1];
                float x2 = L[183 + (t*3 + 2)*9 + d1];
                if (dbl) {
                    x0 += L[183 + (t*3 + 0)*9 + d2];
                    x1 += L[183 + (t*3 + 1)*9 + d2];
                    x2 += L[183 + (t*3 + 2)*9 + d2];
                }
                bv0[t] = x0; bv1[t] = x1; bv2[t] = x2;
            }
#pragma unroll
            for (int uu = 0; uu < 8; ++uu) {
                const int u = n0 + uu;
                const float* wr = &W[6912 + (u * 16 + mm) * 21];
                float a0 = 0.f, a1 = 0.f, a2 = 0.f;
#pragma unroll
                for (int t = 0; t < 21; ++t) {
                    const float wv = wr[t];
                    a0 += wv * bv0[t]; a1 += wv * bv1[t]; a2 += wv * bv2[t];
                }
                dst[(16 + u*3 + 0) * 16] = __float2bfloat16(a0);
                dst[(16 + u*3 + 1) * 16] = __float2bfloat16(a1);
                dst[(16 + u*3 + 2) * 16] = __float2bfloat16(a2);
            }
        }
    }
}

// ---------------------------------------------------------------------------
// build_xt: bid = (b*37 + z)*37 + y. xt[chunk][brow][s][16ch].
// ---------------------------------------------------------------------------
__global__ void build_xt_kernel(
    const float* __restrict__ sv, __hip_bfloat16* __restrict__ xt)
{
    __shared__ float row[2112];                  // 32*66
    const int tid = threadIdx.x;
    const int bid = blockIdx.x;                  // (b*37 + z)*37 + y
    const int y = bid % 37, z = (bid / 37) % 37, b = bid / 1369;
    const bool interior = (z >= 3 && z < 35 && y >= 3 && y < 35);
    if (interior) {
        const float* src = sv + (size_t)b * 2097152 + (z-3) * 1024 + (y-3) * 32;
        for (int f = tid; f < 2048; f += 256) {
            int ch = f >> 5, x = f & 31;
            row[x * 66 + ch] = src[(size_t)ch * 32768 + x];
        }
    }
    __syncthreads();
    for (int e2 = tid; e2 < 3040; e2 += 256) {
        const int chunk = e2 / 304;              // 0..9
        const int r     = e2 - chunk * 304;      // 0..303
        const int s     = r >> 3;                // 0..37
        const int cw    = (r & 7) * 2;
        const int c     = chunk * 16 + cw;
        float v0 = 0.f, v1 = 0.f;
        if (interior && s >= 3 && s < 35) {
            const int x = s - 3;
            if (c < 64) {
                v0 = row[x * 66 + c];
                v1 = row[x * 66 + c + 1];
            } else {
                int q = c - 64, u = q / 6, p = q % 6, i, j;
                pair_ij(p, i, j);
                v0 = row[x * 66 + 16 + u * 3 + i] * row[x * 66 + 16 + u * 3 + j];
                pair_ij(p + 1, i, j);
                v1 = row[x * 66 + 16 + u * 3 + i] * row[x * 66 + 16 + u * 3 + j];
            }
        }
        bf2 w{__float2bfloat16(v0), __float2bfloat16(v1)};
        *(bf2*)(xt + ((size_t)chunk * NROW + bid) * 608 + r * 2) = w;
    }
}

// ---------------------------------------------------------------------------
// Conv (R20 structure + R26 setprio). Grid 512 (2 blocks/CU).
// ---------------------------------------------------------------------------
__global__ __launch_bounds__(256, 2) void conv_mfma_kernel(
    const __hip_bfloat16* __restrict__ xt,
    const __hip_bfloat16* __restrict__ wl,
    __hip_bfloat16* __restrict__ y4b)
{
    __shared__ __align__(16) char lds[LDS_SZ];

    const int phys = blockIdx.x;
    const int bid  = (phys & 7) * (64 * KSN / 8) + (phys >> 3);

    const int low3 = bid & 7;
    const int rest = bid >> 3;
    const int ks   = rest % KSN;
    const int mb   = (rest / KSN) * 8 + low3;   // 0..63
    const int b    = mb >> 4;                   // 0..3
    const int oz   = mb & 15;                   // z-out 0..15

    const int tid  = threadIdx.x;
    const int w    = tid >> 6;
    const int lane = tid & 63;
    const int m    = lane & 31;
    const int h    = lane >> 5;

    int invAE[6]; int nAE = 0;
#pragma unroll
    for (int k = 0; k < 6; ++k) {
        const int i = w + 4 * k;
        if (i < 23) {
            const int o = i * 1024 + lane * 16;
            int r = o / AROW;
            int rem = o - r * AROW;
            if (r > AE_ROWS - 1) { r = AE_ROWS - 1; rem = 0; }
            if (rem >= 1216) rem = 0;
            const int s  = rem >> 5;
            const int cg = ((rem >> 4) & 1) ^ ((s >> 1) & 1);
            invAE[k] = (2 * r) * 608 + s * 16 + cg * 8;
            nAE = k + 1;
        }
    }
    int invAO[6]; int nAO = 0;
#pragma unroll
    for (int k = 0; k < 6; ++k) {
        const int i = w + 4 * k;
        if (i < 22) {
            const int o = i * 1024 + lane * 16;
            int r = o / AROW;
            int rem = o - r * AROW;
            if (r > AO_ROWS - 1) { r = AO_ROWS - 1; rem = 0; }
            if (rem >= 1216) rem = 0;
            const int s  = rem >> 5;
            const int cg = ((rem >> 4) & 1) ^ ((s >> 1) & 1);
            invAO[k] = (2 * r + 1) * 608 + s * 16 + cg * 8;
            nAO = k + 1;
        }
    }
    int invB[4]; int nB = 0;
#pragma unroll
    for (int k = 0; k < 4; ++k) {
        const int i = w + 4 * k;
        if (i < 14) {
            const int kx = i >> 1, nt = i & 1;
            invB[k] = kx * 1024 + (nt * 32 + m) * 16 + h * 8;
            nB = k + 1;
        }
    }

    f16v acc[2][2];
    for (int t = 0; t < 2; ++t)
        for (int n = 0; n < 2; ++n)
            for (int k = 0; k < 16; ++k) acc[t][n][k] = 0.f;

    const int rA0   = ((m >> 4) << 2) + ((m >> 2) & 3);
    const int sbase = (w << 3) + ((m & 3) << 1);

    auto stageAE = [&](int g) {
        const int chunk = g / 7, kz = g - chunk * 7;
        const size_t u = ((size_t)chunk * NROW
                        + (size_t)(b * PZ_ + 2 * oz + kz) * PZ_) * 608;
#pragma unroll
        for (int k = 0; k < 6; ++k)
            if (k < nAE) gl_lds16(xt + u + invAE[k], lds + (w + 4 * k) * 1024);
    };
    auto stageAO = [&](int g) {
        const int chunk = g / 7, kz = g - chunk * 7;
        const size_t u = ((size_t)chunk * NROW
                        + (size_t)(b * PZ_ + 2 * oz + kz) * PZ_) * 608;
#pragma unroll
        for (int k = 0; k < 6; ++k)
            if (k < nAO) gl_lds16(xt + u + invAO[k], lds + AO_OFF + (w + 4 * k) * 1024);
    };
    auto stageB = [&](int g, int kyv, int bsel) {
        const int chunk = g / 7, kz = g - chunk * 7;
        const size_t u = ((size_t)chunk * NTAP + (size_t)(kz * 7 + kyv) * 7) * 1024;
        char* dst = lds + B_OFF + bsel * BSZ;
#pragma unroll
        for (int k = 0; k < 4; ++k)
            if (k < nB) gl_lds16(wl + u + invB[k], dst + (w + 4 * k) * 1024);
    };

    auto compute = [&](int ky, int bsel) {
        const int abase = (ky & 1) ? AO_OFF : 0;
        const char* abp = lds + abase + (rA0 + (ky >> 1)) * AROW;
        const char* bbp = lds + B_OFF + bsel * BSZ;
        __builtin_amdgcn_s_setprio(1);            // T5: favor MFMA waves
#pragma unroll
        for (int kx = 0; kx < 7; ++kx) {
            const int s   = sbase + kx;
            const int cgp = h ^ ((s >> 1) & 1);
            const char* ap = abp + s * 32 + cgp * 16;
            const s8 a0 = *(const s8*)(ap);
            const s8 a1 = *(const s8*)(ap + 8 * AROW);
            const char* bp = bbp + kx * 2048 + h * 512 + m * 16;
            const s8 b0 = *(const s8*)(bp);
            const s8 b1 = *(const s8*)(bp + 1024);
            acc[0][0] = __builtin_amdgcn_mfma_f32_32x32x16_bf16(a0, b0, acc[0][0], 0, 0, 0);
            acc[0][1] = __builtin_amdgcn_mfma_f32_32x32x16_bf16(a0, b1, acc[0][1], 0, 0, 0);
            acc[1][0] = __builtin_amdgcn_mfma_f32_32x32x16_bf16(a1, b0, acc[1][0], 0, 0, 0);
            acc[1][1] = __builtin_amdgcn_mfma_f32_32x32x16_bf16(a1, b1, acc[1][1], 0, 0, 0);
        }
        __builtin_amdgcn_s_setprio(0);
    };

    const int G = (70 - ks + KSN - 1) / KSN;
    const int T = G * 7;
    stageAO(ks);
    stageB(ks, 1, 0);
    __syncthreads();
    int bB = 0;
    for (int t = 0; t < T; ++t) {
        const int gi = t / 7, p = t - gi * 7;
        const int g  = ks + gi * KSN;
        const int ky = (p < 3) ? (2 * p + 1) : (2 * (p - 3));
        const int tn = t + 1;
        if (tn < T) {
            const int gin = tn / 7, pn = tn - gin * 7;
            const int kyn = (pn < 3) ? (2 * pn + 1) : (2 * (pn - 3));
            stageB(ks + gin * KSN, kyn, bB ^ 1);
        }
        if (p == 0) stageAE(g);
        else if (p == 3 && g + KSN < 70) stageAO(g + KSN);
        compute(ky, bB);
        __syncthreads();
        bB ^= 1;
    }

    // epilogue: two-pass LDS transpose, coalesced bf16 partial stores
    const int nl = lane & 31;
    f4* yb = (f4*)lds;
    __hip_bfloat16* dst0 = y4b + (size_t)ks * SLICE_E + (size_t)(b * 64) * 4096;
#pragma unroll
    for (int t = 0; t < 2; ++t) {
        __syncthreads();
#pragma unroll
        for (int nt = 0; nt < 2; ++nt) {
            const int n = nt * 32 + nl;
#pragma unroll
            for (int q = 0; q < 4; ++q) {
                const int rr = 2 * q + h;
                f4 v = { acc[t][nt][4*q], acc[t][nt][4*q+1],
                         acc[t][nt][4*q+2], acc[t][nt][4*q+3] };
                yb[n * 33 + rr * 4 + w] = v;
            }
        }
        __syncthreads();
        for (int j = tid; j < 2048; j += 256) {
            const int n  = j >> 5, sp = j & 31;
            f4 v = yb[n * 33 + sp];
            const int rr = sp >> 2, wq = sp & 3;
            const int yo = t * 8 + (rr >> 2) * 4 + (rr & 3);
            bh4 p{__float2bfloat16(v.x), __float2bfloat16(v.y),
                  __float2bfloat16(v.z), __float2bfloat16(v.w)};
            *(bh4*)(dst0 + (size_t)n * 4096 + oz * 256 + yo * 16 + wq * 4) = p;
        }
    }
}

// ---------------------------------------------------------------------------
// Combine KSN bf16 partials -> f32 yc + per-(n,b) sum of squares. 256 blocks.
// ---------------------------------------------------------------------------
__global__ void combine_reduce_kernel(const __hip_bfloat16* __restrict__ y4b,
                                      float* __restrict__ yc,
                                      float* __restrict__ sums2)
{
    const int n = blockIdx.x & 63, q = blockIdx.x >> 6;
    const size_t base = ((size_t)q * 64 + n) * 4096;
    float s = 0.f;
    for (int i = threadIdx.x; i < 1024; i += 256) {
        const size_t off = base + (size_t)i * 4;
        f4 v = {0.f, 0.f, 0.f, 0.f};
#pragma unroll
        for (int k = 0; k < KSN; ++k) {
            bh4 r = *(const bh4*)(y4b + off + (size_t)k * SLICE_E);
            v.x += (float)r.x; v.y += (float)r.y;
            v.z += (float)r.z; v.w += (float)r.w;
        }
        *(f4*)(yc + off) = v;
        s += v.x * v.x + v.y * v.y + v.z * v.z + v.w * v.w;
    }
    __shared__ float red[256];
    red[threadIdx.x] = s;
    __syncthreads();
    for (int st = 128; st > 0; st >>= 1) {
        if (threadIdx.x < st) red[threadIdx.x] += red[threadIdx.x + st];
        __syncthreads();
    }
    if (threadIdx.x == 0) sums2[n * 4 + q] = red[0];
}

// ---------------------------------------------------------------------------
__global__ void finalize_kernel(const float* __restrict__ yc,
                                const float* __restrict__ sums2,
                                const float* __restrict__ g_s,
                                const float* __restrict__ g_v,
                                const float* __restrict__ bias_s,
                                float* __restrict__ out)
{
    const int idx = blockIdx.x * 256 + threadIdx.x;   // exact grid, 1M
    const int n = (idx >> 12) & 63;
    float v = yc[idx];
    if (n < 16) {
        float sum = sums2[n*4] + sums2[n*4+1] + sums2[n*4+2] + sums2[n*4+3];
        float var = sum * (1.0f / 16384.0f);
        float sc  = g_s[n] / sqrtf(var + 1e-5f);
        v = fmaxf(v * sc + bias_s[n], 0.f);
    } else {
        int u = (n - 16) / 3;
        float sum = 0.f;
        for (int k = 0; k < 12; ++k) sum += sums2[(16 + u * 3) * 4 + k];
        float var = sum * (1.0f / 49152.0f);
        v = v * (g_v[u] / sqrtf(var + 1e-5f));
    }
    out[idx] = v;
}

// ---------------------------------------------------------------------------
extern "C" void kernel_launch(void* const* d_in, const int* in_sizes, int n_in,
                              void* d_out, int out_size, void* d_ws, size_t ws_size,
                              hipStream_t stream)
{
    const float* sv    = (const float*)d_in[0];
    const float* b_ss  = (const float*)d_in[1];
    const float* w_ss  = (const float*)d_in[2];
    const float* b_sv  = (const float*)d_in[3];
    const float* w_sv  = (const float*)d_in[4];
    const float* b_st  = (const float*)d_in[5];
    const float* w_st  = (const float*)d_in[6];
    const float* b_vs  = (const float*)d_in[7];
    const float* w_vs  = (const float*)d_in[8];
    const float* b_vv  = (const float*)d_in[9];
    const float* w_vv  = (const float*)d_in[10];
    const float* b_vt  = (const float*)d_in[11];
    const float* w_vt  = (const float*)d_in[12];
    const float* bn_gs = (const float*)d_in[13];
    const float* bn_gv = (const float*)d_in[14];
    const float* bias_s= (const float*)d_in[15];
    float* out = (float*)d_out;

    char* ws = (char*)d_ws;
    constexpr size_t XT_BYTES = (size_t)10 * NROW * 1216;      // 66,588,160
    constexpr size_t WL_BYTES = (size_t)10 * NTAP * 2048;      //  7,024,640
    constexpr size_t Y4_BYTES = (size_t)KSN * SLICE_E * 2;     // 16,777,216
    constexpr size_t YC_BYTES = (size_t)4 * 64 * 4096 * 4;     //  4,194,304

    __hip_bfloat16* xt  = (__hip_bfloat16*)ws;
    __hip_bfloat16* wl  = (__hip_bfloat16*)(ws + XT_BYTES);
    __hip_bfloat16* y4b = (__hip_bfloat16*)(ws + XT_BYTES + WL_BYTES);
    float* yc    = (float*)(ws + XT_BYTES + WL_BYTES + Y4_BYTES);
    float* sums2 = (float*)(ws + XT_BYTES + WL_BYTES + Y4_BYTES + YC_BYTES);

    build_xt_kernel<<<5476, 256, 0, stream>>>(sv, xt);
    build_w_kernel<<<686, 192, 0, stream>>>(
        b_ss, w_ss, b_sv, w_sv, b_st, w_st, b_vs, w_vs, b_vv, w_vv,
        b_vt, w_vt, wl);
    conv_mfma_kernel<<<64 * KSN, 256, 0, stream>>>(xt, wl, y4b);
    combine_reduce_kernel<<<256, 256, 0, stream>>>(y4b, yc, sums2);
    finalize_kernel<<<4096, 256, 0, stream>>>(yc, sums2, bn_gs, bn_gv, bias_s, out);
}